// Round 1
// baseline (330.485 us; speedup 1.0000x reference)
//
#include <hip/hip_runtime.h>
#include <cstddef>

#define NB 2
#define T_ 4096
#define H_ 32
#define P_ 64
#define N_ 64
#define L_ 64
#define C_ 64
#define LDSP 68   // padded LDS row stride (floats): 68*4B rows keep 16B alignment, banks rotate by 4

// ---------------------------------------------------------------------------
// Kernel 1: per-chunk work. One block per (b, c, h).
//   S      = (C · B^T) ⊙ exp(cs_i - cs_s)  (lower-tri incl. diag, else 0)
//   Y_diag = S · X
//   states[n][p] = sum_i B[i][n] * exp(tot - cs_i) * X[i][p]
// ---------------------------------------------------------------------------
__global__ __launch_bounds__(256) void k1_chunk(
    const float* __restrict__ X, const float* __restrict__ A,
    const float* __restrict__ Bm, const float* __restrict__ Cm,
    float* __restrict__ Y, float* __restrict__ St, float* __restrict__ tot)
{
    __shared__ float sC[L_ * LDSP];   // C tile, later reused to hold S
    __shared__ float sB[L_ * LDSP];
    __shared__ float sX[L_ * LDSP];
    __shared__ float sAcs[L_];
    __shared__ float sDec[L_];        // first raw A, then exp(tot - cs_i)

    const int tid = threadIdx.x;
    const int idx = blockIdx.x;
    const int h  = idx & (H_ - 1);
    const int c  = (idx >> 5) & (C_ - 1);
    const int bb = idx >> 11;
    const int t0 = c * L_;

    if (tid < L_)
        sDec[tid] = A[(size_t)(bb * T_ + t0 + tid) * H_ + h];

    for (int f = tid; f < L_ * 16; f += 256) {
        const int row = f >> 4, c4 = (f & 15) << 2;
        const size_t g = ((size_t)(bb * T_ + t0 + row) * H_ + h) * P_ + c4;
        const float4 vx = *(const float4*)(X + g);
        const float4 vb = *(const float4*)(Bm + g);
        const float4 vc = *(const float4*)(Cm + g);
        float* px = &sX[row * LDSP + c4];
        px[0] = vx.x; px[1] = vx.y; px[2] = vx.z; px[3] = vx.w;
        float* pb = &sB[row * LDSP + c4];
        pb[0] = vb.x; pb[1] = vb.y; pb[2] = vb.z; pb[3] = vb.w;
        float* pc = &sC[row * LDSP + c4];
        pc[0] = vc.x; pc[1] = vc.y; pc[2] = vc.z; pc[3] = vc.w;
    }
    __syncthreads();

    if (tid == 0) {
        float r = 0.f;
        for (int i = 0; i < L_; i++) { r += sDec[i]; sAcs[i] = r; }
        tot[(bb * H_ + h) * C_ + c] = r;
    }
    __syncthreads();
    if (tid < L_) sDec[tid] = expf(sAcs[L_ - 1] - sAcs[tid]);
    __syncthreads();

    const int tx = tid & 15, ty = tid >> 4;
    const int i0 = ty << 2;   // output rows (i / n depending on matmul)
    const int j0 = tx << 2;   // output cols (s / p)

    // ---- matmul 1: S = C · B^T, then decay+mask ----
    float acc[4][4] = {{0.f}};
    for (int n = 0; n < N_; n += 4) {
        float a[4][4], b[4][4];
        #pragma unroll
        for (int k = 0; k < 4; k++) {
            *(float4*)a[k] = *(const float4*)&sC[(i0 + k) * LDSP + n];
            *(float4*)b[k] = *(const float4*)&sB[(j0 + k) * LDSP + n];
        }
        #pragma unroll
        for (int ii = 0; ii < 4; ii++)
            #pragma unroll
            for (int jj = 0; jj < 4; jj++)
                acc[ii][jj] += a[ii][0] * b[jj][0] + a[ii][1] * b[jj][1]
                             + a[ii][2] * b[jj][2] + a[ii][3] * b[jj][3];
    }
    #pragma unroll
    for (int ii = 0; ii < 4; ii++) {
        const float ai = sAcs[i0 + ii];
        #pragma unroll
        for (int jj = 0; jj < 4; jj++) {
            const int s = j0 + jj;
            acc[ii][jj] = (s <= i0 + ii) ? acc[ii][jj] * expf(ai - sAcs[s]) : 0.f;
        }
    }
    __syncthreads();          // everyone done reading sC
    #pragma unroll
    for (int ii = 0; ii < 4; ii++) {
        float* p = &sC[(i0 + ii) * LDSP + j0];
        p[0] = acc[ii][0]; p[1] = acc[ii][1]; p[2] = acc[ii][2]; p[3] = acc[ii][3];
    }
    __syncthreads();

    // ---- matmul 2: Y_diag = S · X ----
    float accY[4][4] = {{0.f}};
    for (int s = 0; s < L_; s += 4) {
        float sr[4][4], xr[4][4];
        #pragma unroll
        for (int k = 0; k < 4; k++) {
            *(float4*)sr[k] = *(const float4*)&sC[(i0 + k) * LDSP + s];
            *(float4*)xr[k] = *(const float4*)&sX[(s + k) * LDSP + j0];
        }
        #pragma unroll
        for (int ii = 0; ii < 4; ii++)
            #pragma unroll
            for (int kk = 0; kk < 4; kk++)
                #pragma unroll
                for (int jj = 0; jj < 4; jj++)
                    accY[ii][jj] += sr[ii][kk] * xr[kk][jj];
    }
    #pragma unroll
    for (int ii = 0; ii < 4; ii++) {
        const size_t g = ((size_t)(bb * T_ + t0 + i0 + ii) * H_ + h) * P_ + j0;
        float4 v; v.x = accY[ii][0]; v.y = accY[ii][1]; v.z = accY[ii][2]; v.w = accY[ii][3];
        *(float4*)(Y + g) = v;
    }

    // ---- matmul 3: states[n][p] = sum_i B[i][n]*dec[i]*X[i][p] ----
    float accS[4][4] = {{0.f}};
    for (int i = 0; i < L_; i += 4) {
        float br[4][4], xr[4][4], dv[4];
        #pragma unroll
        for (int k = 0; k < 4; k++) {
            *(float4*)br[k] = *(const float4*)&sB[(i + k) * LDSP + i0];
            *(float4*)xr[k] = *(const float4*)&sX[(i + k) * LDSP + j0];
            dv[k] = sDec[i + k];
        }
        #pragma unroll
        for (int k = 0; k < 4; k++)
            #pragma unroll
            for (int nn = 0; nn < 4; nn++) {
                const float bd = br[k][nn] * dv[k];
                #pragma unroll
                for (int pp = 0; pp < 4; pp++)
                    accS[nn][pp] += bd * xr[k][pp];
            }
    }
    const size_t sbase = ((size_t)((bb * C_ + c) * H_ + h)) * (N_ * P_);
    #pragma unroll
    for (int nn = 0; nn < 4; nn++) {
        float4 v; v.x = accS[nn][0]; v.y = accS[nn][1]; v.z = accS[nn][2]; v.w = accS[nn][3];
        *(float4*)(St + sbase + (size_t)(i0 + nn) * P_ + j0) = v;
    }
}

// ---------------------------------------------------------------------------
// Kernel 2: inter-chunk scan (in place). Grid = NB*H_*8; each block owns a
// 512-element slice of the 64x64 (n,p) state matrix for one (b,h).
//   NS[c] = carry;  carry = carry*exp(tot_c) + S[c]
// ---------------------------------------------------------------------------
__global__ __launch_bounds__(256) void k2_scan(
    float* __restrict__ St, const float* __restrict__ tot)
{
    const int idx = blockIdx.x;
    const int split = idx & 7;
    const int h  = (idx >> 3) & (H_ - 1);
    const int bb = idx >> 8;
    const int e  = split * 512 + threadIdx.x;
    const float* tp = &tot[(bb * H_ + h) * C_];

    float c0 = 0.f, c1 = 0.f;
    for (int c = 0; c < C_; c++) {
        const float d = expf(tp[c]);
        const size_t base = ((size_t)((bb * C_ + c) * H_ + h)) * (N_ * P_);
        const float t0v = St[base + e];
        const float t1v = St[base + e + 256];
        St[base + e]       = c0;
        St[base + e + 256] = c1;
        c0 = c0 * d + t0v;
        c1 = c1 * d + t1v;
    }
}

// ---------------------------------------------------------------------------
// Kernel 3: off-diagonal contribution.  Y += exp(cs_i) * (C · NS)
// NS stored [n][p]; one block per (b, c, h).
// ---------------------------------------------------------------------------
__global__ __launch_bounds__(256) void k3_off(
    const float* __restrict__ Cm, const float* __restrict__ A,
    const float* __restrict__ St, float* __restrict__ Y)
{
    __shared__ float sC[L_ * LDSP];
    __shared__ float sS[L_ * LDSP];
    __shared__ float sAcs[L_];
    __shared__ float sAtmp[L_];

    const int tid = threadIdx.x;
    const int idx = blockIdx.x;
    const int h  = idx & (H_ - 1);
    const int c  = (idx >> 5) & (C_ - 1);
    const int bb = idx >> 11;
    const int t0 = c * L_;

    if (tid < L_)
        sAtmp[tid] = A[(size_t)(bb * T_ + t0 + tid) * H_ + h];

    const size_t sbase = ((size_t)((bb * C_ + c) * H_ + h)) * (N_ * P_);
    for (int f = tid; f < L_ * 16; f += 256) {
        const int row = f >> 4, c4 = (f & 15) << 2;
        const size_t g = ((size_t)(bb * T_ + t0 + row) * H_ + h) * P_ + c4;
        const float4 vc = *(const float4*)(Cm + g);
        const float4 vs = *(const float4*)(St + sbase + (size_t)row * P_ + c4);
        float* pc = &sC[row * LDSP + c4];
        pc[0] = vc.x; pc[1] = vc.y; pc[2] = vc.z; pc[3] = vc.w;
        float* ps = &sS[row * LDSP + c4];
        ps[0] = vs.x; ps[1] = vs.y; ps[2] = vs.z; ps[3] = vs.w;
    }
    __syncthreads();
    if (tid == 0) {
        float r = 0.f;
        for (int i = 0; i < L_; i++) { r += sAtmp[i]; sAcs[i] = r; }
    }
    __syncthreads();

    const int tx = tid & 15, ty = tid >> 4;
    const int i0 = ty << 2, j0 = tx << 2;

    float acc[4][4] = {{0.f}};
    for (int n = 0; n < N_; n += 4) {
        float cr[4][4], sr[4][4];
        #pragma unroll
        for (int k = 0; k < 4; k++) {
            *(float4*)cr[k] = *(const float4*)&sC[(i0 + k) * LDSP + n];
            *(float4*)sr[k] = *(const float4*)&sS[(n + k) * LDSP + j0];
        }
        #pragma unroll
        for (int ii = 0; ii < 4; ii++)
            #pragma unroll
            for (int kk = 0; kk < 4; kk++)
                #pragma unroll
                for (int jj = 0; jj < 4; jj++)
                    acc[ii][jj] += cr[ii][kk] * sr[kk][jj];
    }
    #pragma unroll
    for (int ii = 0; ii < 4; ii++) {
        const float sc = expf(sAcs[i0 + ii]);
        const size_t g = ((size_t)(bb * T_ + t0 + i0 + ii) * H_ + h) * P_ + j0;
        float4 prev = *(const float4*)(Y + g);
        prev.x += sc * acc[ii][0];
        prev.y += sc * acc[ii][1];
        prev.z += sc * acc[ii][2];
        prev.w += sc * acc[ii][3];
        *(float4*)(Y + g) = prev;
    }
}

extern "C" void kernel_launch(void* const* d_in, const int* in_sizes, int n_in,
                              void* d_out, int out_size, void* d_ws, size_t ws_size,
                              hipStream_t stream)
{
    const float* X  = (const float*)d_in[0];
    const float* A  = (const float*)d_in[1];
    const float* Bm = (const float*)d_in[2];
    const float* Cm = (const float*)d_in[3];
    float* Y   = (float*)d_out;
    float* St  = (float*)d_ws;                              // NB*C_*H_*N_*P_ floats (67 MB)
    float* tot = St + (size_t)NB * C_ * H_ * N_ * P_;       // NB*H_*C_ floats

    k1_chunk<<<NB * C_ * H_, 256, 0, stream>>>(X, A, Bm, Cm, Y, St, tot);
    k2_scan <<<NB * H_ * 8, 256, 0, stream>>>(St, tot);
    k3_off  <<<NB * C_ * H_, 256, 0, stream>>>(Cm, A, St, Y);
}

// Round 2
// 279.343 us; speedup vs baseline: 1.1831x; 1.1831x over previous
//
#include <hip/hip_runtime.h>
#include <cstddef>

#define NB 2
#define T_ 4096
#define H_ 32
#define P_ 64
#define N_ 64
#define L_ 64
#define C_ 64
#define LDB 72   // LDS row stride in bf16 elements (144B rows -> 16B-aligned)

typedef __attribute__((ext_vector_type(8))) short short8;   // 8 bf16 = MFMA A/B frag
typedef __attribute__((ext_vector_type(4))) short short4v;  // 4 bf16 = 8B LDS write
typedef __attribute__((ext_vector_type(4))) float f32x4;    // MFMA C/D frag

// fp32 -> bf16 round-to-nearest-even
static __device__ inline short f2bf(float f) {
    unsigned u = __builtin_bit_cast(unsigned, f);
    u += 0x7fffu + ((u >> 16) & 1u);
    return (short)(u >> 16);
}

// Load one 16x16x32 MFMA fragment from a K-major LDS tile (row=M-or-N idx,
// col=K idx contiguous). A-frag: m=lane&15, k=(lane>>4)*8+j. B-frag mirrors.
// One ds_read_b128 per fragment.
static __device__ inline short8 ldfrag(const short* s, int t16, int kt, int lane) {
    return *(const short8*)(s + (t16 * 16 + (lane & 15)) * LDB + kt * 32 + ((lane >> 4) * 8));
}

// ---------------------------------------------------------------------------
// k1: per-chunk states only.
//   statesT[p][n] = sum_i X[i][p] * B[i][n] * exp(tot - cs_i)   (fp32 out)
// MFMA: M=p (A = X^T, K-major), N=n (B-op = Bdec^T, K-major), K=i.
// Stored [p][n] == reference 'bchpn' layout == k3's B-operand layout for C·NS.
// ---------------------------------------------------------------------------
__global__ __launch_bounds__(256) void k1_states(
    const float* __restrict__ X, const float* __restrict__ A,
    const float* __restrict__ Bm, float* __restrict__ St, float* __restrict__ tot)
{
    __shared__ short sXt[L_ * LDB];   // X^T: [p][i]
    __shared__ short sBt[L_ * LDB];   // (B*dec)^T: [n][i]
    __shared__ float sAcs[L_];

    const int tid = threadIdx.x, lane = tid & 63, wv = tid >> 6;
    const int idx = blockIdx.x;
    const int h  = idx & (H_ - 1);
    const int c  = (idx >> 5) & (C_ - 1);
    const int bb = idx >> 11;
    const int t0 = c * L_;

    // wave 0: parallel inclusive scan of A over the 64-row chunk
    if (wv == 0) {
        float v = A[(size_t)(bb * T_ + t0 + lane) * H_ + h];
        #pragma unroll
        for (int d = 1; d < 64; d <<= 1) {
            float o = __shfl_up(v, (unsigned)d);
            if (lane >= d) v += o;
        }
        sAcs[lane] = v;
        if (lane == 63) tot[(bb * H_ + h) * C_ + c] = v;
    }
    __syncthreads();
    const float totv = sAcs[L_ - 1];

    // stage X,B transposed via 4x4 register blocks (coalesced global float4)
    const int bi = tid >> 4, bp = tid & 15;
    const int i0 = bi * 4, p0 = bp * 4;
    float4 xr[4], br[4];
    #pragma unroll
    for (int k = 0; k < 4; k++) {
        const size_t g = ((size_t)(bb * T_ + t0 + i0 + k) * H_ + h) * P_ + p0;
        xr[k] = *(const float4*)(X + g);
        br[k] = *(const float4*)(Bm + g);
    }
    float dec[4];
    #pragma unroll
    for (int k = 0; k < 4; k++) dec[k] = expf(totv - sAcs[i0 + k]);
    #pragma unroll
    for (int j = 0; j < 4; j++) {
        short4v vx, vb;
        #pragma unroll
        for (int k = 0; k < 4; k++) {
            vx[k] = f2bf(((const float*)&xr[k])[j]);
            vb[k] = f2bf(((const float*)&br[k])[j] * dec[k]);
        }
        *(short4v*)&sXt[(p0 + j) * LDB + i0] = vx;
        *(short4v*)&sBt[(p0 + j) * LDB + i0] = vb;
    }
    __syncthreads();

    // wave wv owns p-band [16wv, 16wv+16)
    const short8 a0 = ldfrag(sXt, wv, 0, lane);
    const short8 a1 = ldfrag(sXt, wv, 1, lane);
    const size_t sbase = ((size_t)((bb * C_ + c) * H_ + h)) * (N_ * P_);
    const int prow = wv * 16 + (lane >> 4) * 4;
    const int ncol = lane & 15;
    #pragma unroll
    for (int nt = 0; nt < 4; nt++) {
        f32x4 acc = {0.f, 0.f, 0.f, 0.f};
        acc = __builtin_amdgcn_mfma_f32_16x16x32_bf16(a0, ldfrag(sBt, nt, 0, lane), acc, 0, 0, 0);
        acc = __builtin_amdgcn_mfma_f32_16x16x32_bf16(a1, ldfrag(sBt, nt, 1, lane), acc, 0, 0, 0);
        #pragma unroll
        for (int r = 0; r < 4; r++)
            St[sbase + (size_t)(prow + r) * N_ + nt * 16 + ncol] = acc[r];
    }
}

// ---------------------------------------------------------------------------
// k2: inter-chunk scan, in place, fp32 (unchanged from passing version).
//   NS[c] = carry;  carry = carry*exp(tot_c) + S[c]
// ---------------------------------------------------------------------------
__global__ __launch_bounds__(256) void k2_scan(
    float* __restrict__ St, const float* __restrict__ tot)
{
    const int idx = blockIdx.x;
    const int split = idx & 7;
    const int h  = (idx >> 3) & (H_ - 1);
    const int bb = idx >> 8;
    const int e  = split * 512 + threadIdx.x;
    const float* tp = &tot[(bb * H_ + h) * C_];

    float c0 = 0.f, c1 = 0.f;
    for (int c = 0; c < C_; c++) {
        const float d = expf(tp[c]);
        const size_t base = ((size_t)((bb * C_ + c) * H_ + h)) * (N_ * P_);
        const float t0v = St[base + e];
        const float t1v = St[base + e + 256];
        St[base + e]       = c0;
        St[base + e + 256] = c1;
        c0 = c0 * d + t0v;
        c1 = c1 * d + t1v;
    }
}

// ---------------------------------------------------------------------------
// k3: full output.
//   S = (C·B^T) ⊙ tril-exp(cs_i - cs_s)      (MFMA, natural layouts)
//   Y = S·X + exp(cs_i) * (C·NS)             (MFMA; single Y write, no RMW)
// ---------------------------------------------------------------------------
__global__ __launch_bounds__(256) void k3_out(
    const float* __restrict__ X, const float* __restrict__ A,
    const float* __restrict__ Bm, const float* __restrict__ Cm,
    const float* __restrict__ St, float* __restrict__ Y)
{
    __shared__ short sC [L_ * LDB];   // C: [i][n]      (natural, n contiguous)
    __shared__ short sB [L_ * LDB];   // B: [s][n]      (natural)
    __shared__ short sXt[L_ * LDB];   // X^T: [p][s]
    __shared__ short sNS[L_ * LDB];   // NS^T: [p][n]   (St already stored [p][n])
    __shared__ short sS [L_ * LDB];   // S: [i][s]
    __shared__ float sAcs[L_];

    const int tid = threadIdx.x, lane = tid & 63, wv = tid >> 6;
    const int idx = blockIdx.x;
    const int h  = idx & (H_ - 1);
    const int c  = (idx >> 5) & (C_ - 1);
    const int bb = idx >> 11;
    const int t0 = c * L_;
    const size_t sbase = ((size_t)((bb * C_ + c) * H_ + h)) * (N_ * P_);

    if (wv == 0) {
        float v = A[(size_t)(bb * T_ + t0 + lane) * H_ + h];
        #pragma unroll
        for (int d = 1; d < 64; d <<= 1) {
            float o = __shfl_up(v, (unsigned)d);
            if (lane >= d) v += o;
        }
        sAcs[lane] = v;
    }

    // natural-layout staging: C, B, NS
    #pragma unroll
    for (int f = tid; f < L_ * 16; f += 256) {
        const int row = f >> 4, c4 = (f & 15) << 2;
        const size_t g = ((size_t)(bb * T_ + t0 + row) * H_ + h) * P_ + c4;
        const float4 vc = *(const float4*)(Cm + g);
        const float4 vb = *(const float4*)(Bm + g);
        const float4 vs = *(const float4*)(St + sbase + (size_t)row * N_ + c4);
        short4v c2, b2, s2;
        #pragma unroll
        for (int k = 0; k < 4; k++) {
            c2[k] = f2bf(((const float*)&vc)[k]);
            b2[k] = f2bf(((const float*)&vb)[k]);
            s2[k] = f2bf(((const float*)&vs)[k]);
        }
        *(short4v*)&sC [row * LDB + c4] = c2;
        *(short4v*)&sB [row * LDB + c4] = b2;
        *(short4v*)&sNS[row * LDB + c4] = s2;
    }
    // transposed staging: X^T
    {
        const int bi = tid >> 4, bp = tid & 15;
        const int i0 = bi * 4, p0 = bp * 4;
        float4 xr[4];
        #pragma unroll
        for (int k = 0; k < 4; k++) {
            const size_t g = ((size_t)(bb * T_ + t0 + i0 + k) * H_ + h) * P_ + p0;
            xr[k] = *(const float4*)(X + g);
        }
        #pragma unroll
        for (int j = 0; j < 4; j++) {
            short4v vx;
            #pragma unroll
            for (int k = 0; k < 4; k++) vx[k] = f2bf(((const float*)&xr[k])[j]);
            *(short4v*)&sXt[(p0 + j) * LDB + i0] = vx;
        }
    }
    __syncthreads();

    // wave wv owns output row band i in [16wv, 16wv+16)
    const short8 c0f = ldfrag(sC, wv, 0, lane);
    const short8 c1f = ldfrag(sC, wv, 1, lane);
    const int rbase = wv * 16 + (lane >> 4) * 4;   // C/D rows for this lane
    const int col   = lane & 15;

    // Y_off partial: C · NS  (keep in regs, scale later)
    f32x4 accO[4];
    #pragma unroll
    for (int pt = 0; pt < 4; pt++) {
        f32x4 a = {0.f, 0.f, 0.f, 0.f};
        a = __builtin_amdgcn_mfma_f32_16x16x32_bf16(c0f, ldfrag(sNS, pt, 0, lane), a, 0, 0, 0);
        a = __builtin_amdgcn_mfma_f32_16x16x32_bf16(c1f, ldfrag(sNS, pt, 1, lane), a, 0, 0, 0);
        accO[pt] = a;
    }

    // S = C·B^T, mask + decay, write to LDS in A-operand (row-major) layout.
    float csr[4];
    #pragma unroll
    for (int r = 0; r < 4; r++) csr[r] = sAcs[rbase + r];
    #pragma unroll
    for (int st = 0; st < 4; st++) {
        f32x4 a = {0.f, 0.f, 0.f, 0.f};
        a = __builtin_amdgcn_mfma_f32_16x16x32_bf16(c0f, ldfrag(sB, st, 0, lane), a, 0, 0, 0);
        a = __builtin_amdgcn_mfma_f32_16x16x32_bf16(c1f, ldfrag(sB, st, 1, lane), a, 0, 0, 0);
        const int scol = st * 16 + col;
        const float ccs = sAcs[scol];
        #pragma unroll
        for (int r = 0; r < 4; r++) {
            const float v = (scol <= rbase + r) ? a[r] * expf(csr[r] - ccs) : 0.f;
            sS[(rbase + r) * LDB + scol] = f2bf(v);
        }
    }
    // NOTE: no __syncthreads needed — wave wv wrote exactly rows [16wv,16wv+16)
    // of sS and reads only those rows below; same-wave LDS ordering suffices.

    const short8 s0f = ldfrag(sS, wv, 0, lane);
    const short8 s1f = ldfrag(sS, wv, 1, lane);
    float exr[4];
    #pragma unroll
    for (int r = 0; r < 4; r++) exr[r] = expf(csr[r]);
    #pragma unroll
    for (int pt = 0; pt < 4; pt++) {
        f32x4 a = {0.f, 0.f, 0.f, 0.f};
        a = __builtin_amdgcn_mfma_f32_16x16x32_bf16(s0f, ldfrag(sXt, pt, 0, lane), a, 0, 0, 0);
        a = __builtin_amdgcn_mfma_f32_16x16x32_bf16(s1f, ldfrag(sXt, pt, 1, lane), a, 0, 0, 0);
        #pragma unroll
        for (int r = 0; r < 4; r++) {
            const size_t g = ((size_t)(bb * T_ + t0 + rbase + r) * H_ + h) * P_ + pt * 16 + col;
            Y[g] = a[r] + exr[r] * accO[pt][r];
        }
    }
}

extern "C" void kernel_launch(void* const* d_in, const int* in_sizes, int n_in,
                              void* d_out, int out_size, void* d_ws, size_t ws_size,
                              hipStream_t stream)
{
    const float* X  = (const float*)d_in[0];
    const float* A  = (const float*)d_in[1];
    const float* Bm = (const float*)d_in[2];
    const float* Cm = (const float*)d_in[3];
    float* Y   = (float*)d_out;
    float* St  = (float*)d_ws;                              // NB*C_*H_*P_*N_ floats (67 MB)
    float* tot = St + (size_t)NB * C_ * H_ * N_ * P_;       // NB*H_*C_ floats

    k1_states<<<NB * C_ * H_, 256, 0, stream>>>(X, A, Bm, St, tot);
    k2_scan  <<<NB * H_ * 8, 256, 0, stream>>>(St, tot);
    k3_out   <<<NB * C_ * H_, 256, 0, stream>>>(X, A, Bm, Cm, St, Y);
}